// Round 4
// baseline (1005.402 us; speedup 1.0000x reference)
//
#include <hip/hip_runtime.h>

#define L_SEQ 2048
#define CH    1024
#define NB    32
#define KSEL  20

typedef short v8s  __attribute__((ext_vector_type(8)));
typedef float v16f __attribute__((ext_vector_type(16)));

// ---------------- workspace layout (float offsets) ----------------
#define WS_XSUM   0          // [32*1024] f32   column sums of x
#define WS_YMAX   32768      // [32*1024] u32   encoded col-max of y
#define WS_M1     65536      // [32*1024] f32   mean-pool @ W^T + b
#define WS_AMAX   98304      // [32*1024] f32   decoded max-pool + b
#define WS_T1     131072     // [32*1024] f32
#define WS_T2     163840     // [32*1024] f32
#define WS_P      196608     // [32*1024] f32   gn1(t1)+gn2(t2)
#define WS_V      294912     // [32*1024] f32   v = Wc^T p
#define WS_S      327680     // [32*2048] f32   logit sums
#define WS_TOPK   393216     // [640] int
#define WS_BC     394240     // [1024] f32      bc = W1 b + b1
#define WS_WC     395264     // [1024*1024] f32 Wc = W1 W (row-major [d][c])
#define WS_WPAK   1443840    // 4 MB: packed W  (frag-major split-bf16)
#define WS_WTPAK  2492416    // 4 MB: packed W^T; REUSED later for packed Wc

// ---------------- fp32 -> (hi,lo) bf16 split, 8 elems -> two uint4 ----------------
__device__ __forceinline__ void split8(float4 qa, float4 qb, uint4& hi, uint4& lo) {
  float f[8] = {qa.x, qa.y, qa.z, qa.w, qb.x, qb.y, qb.z, qb.w};
  unsigned h[8], l[8];
  #pragma unroll
  for (int e = 0; e < 8; ++e) {
    unsigned u  = __float_as_uint(f[e]);
    unsigned hu = u & 0xFFFF0000u;                 // truncated hi bf16
    float lf    = f[e] - __uint_as_float(hu);      // residual
    h[e] = u >> 16;
    l[e] = __float_as_uint(lf) >> 16;              // truncated lo bf16
  }
  hi.x = h[0] | (h[1] << 16); hi.y = h[2] | (h[3] << 16);
  hi.z = h[4] | (h[5] << 16); hi.w = h[6] | (h[7] << 16);
  lo.x = l[0] | (l[1] << 16); lo.y = l[2] | (l[3] << 16);
  lo.z = l[4] | (l[5] << 16); lo.w = l[6] | (l[7] << 16);
}

// ---------------- pack body: row-major M -> frag-major split-bf16 ----------------
// chunk (Rw, kt) = 1024 uint4; slot = ((r>>5)*2 + (p>>1))*128 + (p&1)*32 + (r&31)
__device__ __forceinline__ void pack_row_body(const float* __restrict__ W,
                                              uint4* __restrict__ wp,
                                              int Rw, int kt, int t) {
  const float* wb = W + (size_t)Rw * 128 * CH;
  uint4* out = wp + ((size_t)Rw * 32 + kt) * 1024;
  #pragma unroll
  for (int pass = 0; pass < 2; ++pass) {
    int idx = pass * 256 + t;
    int r = idx >> 2, p = idx & 3;
    const float* ap = wb + (size_t)r * CH + kt * 32 + p * 8;
    float4 f0 = *(const float4*)ap;
    float4 f1 = *(const float4*)(ap + 4);
    uint4 hi, lo;
    split8(f0, f1, hi, lo);
    int slot = ((r >> 5) * 2 + (p >> 1)) * 128 + (p & 1) * 32 + (r & 31);
    out[slot] = hi;
    out[slot + 64] = lo;
  }
}

// ---------------- pack body: W^T (LDS transpose) -> frag-major split-bf16 --------
__device__ __forceinline__ void pack_tr_body(const float* __restrict__ W,
                                             uint4* __restrict__ wtp,
                                             int cc, int kt, int t,
                                             float (*__restrict__ Wl)[129]) {
  #pragma unroll
  for (int it = 0; it < 16; ++it) {
    int idx = it * 256 + t;
    int el = idx >> 7, cl = idx & 127;
    Wl[el][cl] = W[(size_t)(kt * 32 + el) * CH + cc * 128 + cl];
  }
  __syncthreads();
  uint4* out = wtp + ((size_t)cc * 32 + kt) * 1024;
  #pragma unroll
  for (int pass = 0; pass < 2; ++pass) {
    int sid = pass * 256 + t;
    int r = sid >> 2, p = sid & 3;
    float f[8];
    #pragma unroll
    for (int q = 0; q < 8; ++q) f[q] = Wl[p * 8 + q][r];
    float4 f0 = {f[0], f[1], f[2], f[3]}, f1 = {f[4], f[5], f[6], f[7]};
    uint4 hi, lo;
    split8(f0, f1, hi, lo);
    int slot = ((r >> 5) * 2 + (p >> 1)) * 128 + (p & 1) * 32 + (r & 31);
    out[slot] = hi;
    out[slot + 64] = lo;
  }
}

// ---------------- fused prologue: pack W, pack W^T, bc = W1 b + b1, zero-inits ----
// grid (32, 20): y 0..7 packw + zero xsum/ymax/v; y 8..15 packwt + zero Wc;
//                y 16..19 bc. No intra-kernel consumers of the zeroed buffers.
__global__ __launch_bounds__(256) void prep_kernel(const float* __restrict__ W,
                                                   const float* __restrict__ W1,
                                                   const float* __restrict__ b,
                                                   const float* __restrict__ b1,
                                                   uint4* __restrict__ wp,
                                                   uint4* __restrict__ wtp,
                                                   float* __restrict__ wsf,
                                                   float* __restrict__ bc) {
  __shared__ float Wl[32][129];
  int t = threadIdx.x, x = blockIdx.x, y = blockIdx.y;
  if (y < 8) {
    int flat = (y * 32 + x) * 256 + t;          // [0, 65536): xsum + ymax
    wsf[WS_XSUM + flat] = 0.f;
    if (flat < 32768) wsf[WS_V + flat] = 0.f;
    pack_row_body(W, wp, y, x, t);
  } else if (y < 16) {
    int tid = ((y - 8) * 32 + x) * 256 + t;     // [0, 65536): zero Wc (1M floats)
    float4* wc4 = (float4*)(wsf + WS_WC);
    #pragma unroll
    for (int r = 0; r < 4; ++r) wc4[(size_t)tid * 4 + r] = float4{0.f, 0.f, 0.f, 0.f};
    pack_tr_body(W, wtp, y - 8, x, t, Wl);
  } else {
    int bk = (y - 16) * 32 + x;                 // [0, 128)
    int d = bk * 8 + (t >> 5);
    int lane = t & 31;
    const float4* wr = (const float4*)(W1 + (size_t)d * CH);
    const float4* br = (const float4*)b;
    float acc = 0.f;
    #pragma unroll
    for (int c = lane; c < 256; c += 32) {
      float4 a = wr[c], m = br[c];
      acc += a.x * m.x + a.y * m.y + a.z * m.z + a.w * m.w;
    }
    #pragma unroll
    for (int off = 16; off; off >>= 1) acc += __shfl_xor(acc, off);
    if (lane == 0) bc[d] = acc + b1[d];
  }
}

// ---------------- column sums of x (atomic partial sums) ----------------
// Standalone: its 256 MB stream evicts the packed-W L2 panels, so it must NOT
// co-reside with the MFMA gemm (round-3 postmortem: fused -> MfmaUtil 57->40).
__global__ __launch_bounds__(256) void mean_kernel(const float* __restrict__ x,
                                                   float* __restrict__ xsum) {
  int b = blockIdx.y, chunk = blockIdx.x, t = threadIdx.x;
  const float4* bp = (const float4*)(x + ((size_t)b * L_SEQ + (size_t)chunk * 64) * CH);
  float sx = 0.f, sy = 0.f, sz = 0.f, sw = 0.f;
  #pragma unroll 4
  for (int l = 0; l < 64; ++l) {
    float4 a = bp[l * 256 + t];
    sx += a.x; sy += a.y; sz += a.z; sw += a.w;
  }
  float* dst = xsum + b * CH + t * 4;
  atomicAdd(dst + 0, sx); atomicAdd(dst + 1, sy);
  atomicAdd(dst + 2, sz); atomicAdd(dst + 3, sw);
}

// ---------------- shared GEMM K-loop core ----------------
// Block 128m x 256n, 4 waves, wave w = wn: tile 128m x 64n (i:4 m-tiles, j:2 n-tiles).
// A: f32 -> split -> LDS dbuf (conflict-free). B: packed frag direct from global (L2).
// split+store of kt+1 sits BETWEEN s=0 and s=1: A-loads (issued at kt start, ~900cy
// HBM latency) land right as s0's MFMAs finish; the ds_writes then drain under s1's
// MFMA issue, so the pre-barrier s_waitcnt drain is clean.
template<bool FOURTH, int NKT>
__device__ __forceinline__ void gemm_core(const float* __restrict__ arow,
                                          const uint4* __restrict__ wbB,
                                          const int cgbase,
                                          uint4 (*__restrict__ smA)[1024],
                                          const int w, const int lane,
                                          v16f acc[4][2]) {
  {  // stage kt=0 into buf 0
    float4 p0 = *(const float4*)(arow);
    float4 p1 = *(const float4*)(arow + 4);
    float4 p2 = *(const float4*)(arow + 16);
    float4 p3 = *(const float4*)(arow + 20);
    uint4 hi, lo;
    split8(p0, p1, hi, lo);
    smA[0][(w * 2 + 0) * 128 + lane] = hi;
    smA[0][(w * 2 + 0) * 128 + 64 + lane] = lo;
    split8(p2, p3, hi, lo);
    smA[0][(w * 2 + 1) * 128 + lane] = hi;
    smA[0][(w * 2 + 1) * 128 + 64 + lane] = lo;
  }
  v8s bc[4], bn[4];
  #pragma unroll
  for (int j = 0; j < 2; ++j) {
    bc[j * 2]     = *(const v8s*)&wbB[((cgbase + j) * 2 + 0) * 128];
    bc[j * 2 + 1] = *(const v8s*)&wbB[((cgbase + j) * 2 + 0) * 128 + 64];
  }
  __syncthreads();

  for (int kt = 0; kt < NKT; ++kt) {
    const int cur = kt & 1;
    float4 q0, q1, q2, q3;
    if (kt < NKT - 1) {                 // issue next A-slice loads early
      const float* an = arow + (kt + 1) * 32;
      q0 = *(const float4*)(an);
      q1 = *(const float4*)(an + 4);
      q2 = *(const float4*)(an + 16);
      q3 = *(const float4*)(an + 20);
    }
    #pragma unroll
    for (int s = 0; s < 2; ++s) {
      const int nkt = s ? kt + 1 : kt, ns = s ^ 1;
      if (nkt < NKT) {                  // prefetch next B half-slice (4 loads)
        #pragma unroll
        for (int j = 0; j < 2; ++j) {
          bn[j * 2]     = *(const v8s*)&wbB[(size_t)nkt * 1024 + ((cgbase + j) * 2 + ns) * 128];
          bn[j * 2 + 1] = *(const v8s*)&wbB[(size_t)nkt * 1024 + ((cgbase + j) * 2 + ns) * 128 + 64];
        }
      }
      v8s ah[4], al[4];
      #pragma unroll
      for (int i = 0; i < 4; ++i) {
        int base = (i * 2 + s) * 128 + lane;
        ah[i] = *(const v8s*)&smA[cur][base];
        al[i] = *(const v8s*)&smA[cur][base + 64];
      }
      #pragma unroll
      for (int j = 0; j < 2; ++j) {
        v8s bh = bc[j * 2], bl = bc[j * 2 + 1];
        #pragma unroll
        for (int i = 0; i < 4; ++i) {
          acc[i][j] = __builtin_amdgcn_mfma_f32_32x32x16_bf16(ah[i], bh, acc[i][j], 0, 0, 0);
          acc[i][j] = __builtin_amdgcn_mfma_f32_32x32x16_bf16(ah[i], bl, acc[i][j], 0, 0, 0);
          acc[i][j] = __builtin_amdgcn_mfma_f32_32x32x16_bf16(al[i], bh, acc[i][j], 0, 0, 0);
          if (FOURTH)
            acc[i][j] = __builtin_amdgcn_mfma_f32_32x32x16_bf16(al[i], bl, acc[i][j], 0, 0, 0);
        }
      }
      #pragma unroll
      for (int e = 0; e < 4; ++e) bc[e] = bn[e];
      if (s == 0 && kt < NKT - 1) {     // mid-kt: split + store kt+1 into other buf
        uint4 hi, lo;
        split8(q0, q1, hi, lo);
        smA[cur ^ 1][(w * 2 + 0) * 128 + lane] = hi;
        smA[cur ^ 1][(w * 2 + 0) * 128 + 64 + lane] = lo;
        split8(q2, q3, hi, lo);
        smA[cur ^ 1][(w * 2 + 1) * 128 + lane] = hi;
        smA[cur ^ 1][(w * 2 + 1) * 128 + 64 + lane] = lo;
      }
    }
    __syncthreads();
  }
}

// ---------------- fused: big GEMM+colmax  ||  Wc = W1@W ----------------
// grid = 2176 = 128 groups of 17: r<16 -> gemm block (2048), r==16 -> wc (128).
// mean is deliberately NOT here: its 256 MB x-stream evicts the packed-W panels
// from L2 and stalls the B-path (round-3: MfmaUtil 57->40, +310 MB FETCH).
// wc's L2 footprint is bounded (~32 MB wtpak re-reads, transient) -> harmless.
__global__ __launch_bounds__(256, 2) void fused3_kernel(const float* __restrict__ X,
                                                        const uint4* __restrict__ wp,
                                                        unsigned* __restrict__ ymax,
                                                        const float* __restrict__ W1,
                                                        const uint4* __restrict__ wtp,
                                                        float* __restrict__ Wc) {
  __shared__ uint4 smA[2][1024];        // 32 KB dbuf -> 2 blocks/CU
  const int id = blockIdx.x;
  const int g = id / 17, r = id % 17;
  const int t = threadIdx.x, lane = t & 63, w = t >> 6;

  if (r < 16) {
    // ---------- big GEMM + column max (3-term split-bf16) ----------
    const int k = g * 16 + r;
    const int strip = k & 3, mt = k >> 2;
    const int batch = mt >> 4;
    const float* arow = X + (size_t)(mt * 128 + w * 32 + (lane & 31)) * CH + (lane >> 5) * 8;
    v16f acc[4][2];
    #pragma unroll
    for (int i = 0; i < 4; ++i)
      #pragma unroll
      for (int j = 0; j < 2; ++j)
        #pragma unroll
        for (int e = 0; e < 16; ++e) acc[i][j][e] = 0.f;
    const uint4* wbB = wp + (size_t)(strip * 2 + (w >> 1)) * 32768 + lane;
    gemm_core<false, 32>(arow, wbB, (w & 1) * 2, smA, w, lane, acc);

    // column-max epilogue: 32x32 C/D layout, col = lane&31
    #pragma unroll
    for (int j = 0; j < 2; ++j) {
      float m = -INFINITY;
      #pragma unroll
      for (int i = 0; i < 4; ++i)
        #pragma unroll
        for (int e = 0; e < 16; ++e) m = fmaxf(m, acc[i][j][e]);
      m = fmaxf(m, __shfl_xor(m, 32));
      if (lane < 32) {
        int col = strip * 256 + w * 64 + j * 32 + lane;
        unsigned u = __float_as_uint(m);
        unsigned enc = (m >= 0.f) ? (u | 0x80000000u) : ~u;  // order-preserving encode
        atomicMax(&ymax[batch * CH + col], enc);
      }
    }
  } else {
    // ---------- Wc = W1 @ W (4-term, K-split x4, atomic reduction) ----------
    const int c = g;                    // 0..127
    const int blk = c >> 2, chunk = c & 3;
    const int strip = blk & 3, mt = blk >> 2;     // mt 0..7
    const float* arow = W1 + (size_t)(mt * 128 + w * 32 + (lane & 31)) * CH
                           + (lane >> 5) * 8 + chunk * 256;
    v16f acc[4][2];
    #pragma unroll
    for (int i = 0; i < 4; ++i)
      #pragma unroll
      for (int j = 0; j < 2; ++j)
        #pragma unroll
        for (int e = 0; e < 16; ++e) acc[i][j][e] = 0.f;
    const uint4* wbB = wtp + (size_t)(strip * 2 + (w >> 1)) * 32768
                           + (size_t)chunk * (8 * 1024) + lane;
    gemm_core<true, 8>(arow, wbB, (w & 1) * 2, smA, w, lane, acc);

    #pragma unroll
    for (int i = 0; i < 4; ++i)
      #pragma unroll
      for (int j = 0; j < 2; ++j)
        #pragma unroll
        for (int rr = 0; rr < 16; ++rr) {
          int row = (rr & 3) + 8 * (rr >> 2) + 4 * (lane >> 5);
          int grow = mt * 128 + i * 32 + row;
          int gcol = strip * 256 + w * 64 + j * 32 + (lane & 31);
          atomicAdd(&Wc[(size_t)grow * CH + gcol], acc[i][j][rr]);
        }
  }
}

// ---------------- out += x[sel] @ Wc^T (4-term; bias pre-broadcast by gnp) -------
// K-split x8 (blockIdx.y = chunk, 4 kt each); fp32 atomic reduction into d_out.
__global__ __launch_bounds__(256, 2) void out_gemm(const float* __restrict__ X,
                                                   const int* __restrict__ idx,
                                                   const uint4* __restrict__ wcp,
                                                   float* __restrict__ C) {
  __shared__ uint4 smA[2][1024];
  const int t = threadIdx.x, lane = t & 63, w = t >> 6;
  const int blk = blockIdx.x, chunk = blockIdx.y;   // blk 0..19, chunk 0..7
  const int strip = blk & 3, mt = blk >> 2;         // mt 0..4 (640 rows exactly)
  const int rr = mt * 128 + w * 32 + (lane & 31);
  const int grow_a = (rr / KSEL) * L_SEQ + idx[rr];
  const float* arow = X + (size_t)grow_a * CH + (lane >> 5) * 8 + chunk * 128;
  v16f acc[4][2];
  #pragma unroll
  for (int i = 0; i < 4; ++i)
    #pragma unroll
    for (int j = 0; j < 2; ++j)
      #pragma unroll
      for (int e = 0; e < 16; ++e) acc[i][j][e] = 0.f;
  const uint4* wbB = wcp + (size_t)(strip * 2 + (w >> 1)) * 32768
                         + (size_t)chunk * (4 * 1024) + lane;
  gemm_core<true, 4>(arow, wbB, (w & 1) * 2, smA, w, lane, acc);

  #pragma unroll
  for (int i = 0; i < 4; ++i)
    #pragma unroll
    for (int j = 0; j < 2; ++j)
      #pragma unroll
      for (int r = 0; r < 16; ++r) {
        int row = (r & 3) + 8 * (r >> 2) + 4 * (lane >> 5);
        int grow = mt * 128 + i * 32 + row;
        int gcol = strip * 256 + w * 64 + j * 32 + (lane & 31);
        atomicAdd(&C[(size_t)grow * CH + gcol], acc[i][j][r]);
      }
}

// ---------------- fused: repack Wc  ||  poolmix ----------------
// id<256: wtpak := packed Wc; id>=256: m1 = xsum@W^T/2048 + b, amax = decode + b.
__global__ __launch_bounds__(256) void mid_kernel(const float* __restrict__ Wc,
                                                  uint4* __restrict__ wtp,
                                                  const float* __restrict__ xsum,
                                                  const unsigned* __restrict__ ymax,
                                                  const float* __restrict__ W,
                                                  const float* __restrict__ bias,
                                                  float* __restrict__ m1,
                                                  float* __restrict__ amax) {
  int id = blockIdx.x, t = threadIdx.x;
  if (id < 256) {
    pack_row_body(Wc, wtp, id >> 5, id & 31, t);
  } else {
    int bk = id - 256;                  // 0..127
    int iid = bk * 256 + t;
    unsigned u = ymax[iid];
    float f = (u & 0x80000000u) ? __uint_as_float(u & 0x7FFFFFFFu) : __uint_as_float(~u);
    amax[iid] = f + bias[iid & (CH - 1)];

    int d = bk * 8 + (t >> 5);
    int b = t & 31;
    const float4* Ir = (const float4*)(xsum + b * CH);
    const float4* Mr = (const float4*)(W + (size_t)d * CH);
    float acc = 0.f;
    #pragma unroll 4
    for (int c = 0; c < CH / 4; ++c) {
      float4 a = Ir[c], m = Mr[c];
      acc += a.x * m.x + a.y * m.y + a.z * m.z + a.w * m.w;
    }
    m1[b * CH + d] = acc * (1.f / 2048.f) + bias[d];
  }
}

// ---------------- t1 = m1@Wm^T + bm ; t2 = amax@Wa^T + ba ----------------
__global__ __launch_bounds__(256) void lin2_kernel(const float* __restrict__ m1,
                                                   const float* __restrict__ amax,
                                                   const float* __restrict__ Wm,
                                                   const float* __restrict__ bm,
                                                   const float* __restrict__ Wa,
                                                   const float* __restrict__ ba,
                                                   float* __restrict__ t1,
                                                   float* __restrict__ t2) {
  int t = threadIdx.x;
  int which = blockIdx.x >> 7, bk = blockIdx.x & 127;
  const float* I = which ? amax : m1;
  const float* M = which ? Wa : Wm;
  const float* bb = which ? ba : bm;
  float* O = which ? t2 : t1;
  int d = bk * 8 + (t >> 5);
  int b = t & 31;
  const float4* Ir = (const float4*)(I + b * CH);
  const float4* Mr = (const float4*)(M + (size_t)d * CH);
  float acc = 0.f;
  #pragma unroll 4
  for (int c = 0; c < CH / 4; ++c) {
    float4 a = Ir[c], m = Mr[c];
    acc += a.x * m.x + a.y * m.y + a.z * m.z + a.w * m.w;
  }
  O[b * CH + d] = acc + bb[d];
}

// ---------------- GroupNorm both branches, emit p = gn1(t1)+gn2(t2) ----------------
// Also pre-broadcasts bc into d_out so K-split out_gemm can atomicAdd.
__global__ __launch_bounds__(1024) void gnp_kernel(const float* __restrict__ t1,
                                                   const float* __restrict__ t2,
                                                   const float* __restrict__ g1w, const float* __restrict__ g1b,
                                                   const float* __restrict__ g2w, const float* __restrict__ g2b,
                                                   float* __restrict__ p,
                                                   const float* __restrict__ bc,
                                                   float* __restrict__ dout) {
  int b = blockIdx.x, c = threadIdx.x;
  float v1 = t1[b * CH + c], v2 = t2[b * CH + c];
  float s1 = v1, s2 = v2;
  #pragma unroll
  for (int off = 16; off; off >>= 1) { s1 += __shfl_xor(s1, off); s2 += __shfl_xor(s2, off); }
  float d1 = v1 - s1 * (1.f / 32.f), d2 = v2 - s2 * (1.f / 32.f);
  float q1 = d1 * d1, q2 = d2 * d2;
  #pragma unroll
  for (int off = 16; off; off >>= 1) { q1 += __shfl_xor(q1, off); q2 += __shfl_xor(q2, off); }
  float o1 = d1 * rsqrtf(q1 * (1.f / 32.f) + 1e-5f) * g1w[c] + g1b[c];
  float o2 = d2 * rsqrtf(q2 * (1.f / 32.f) + 1e-5f) * g2w[c] + g2b[c];
  p[b * CH + c] = o1 + o2;

  // d_out[r*32 + b][c] = bc[c] for r = 0..19  (flat = r*32768 + b*1024 + c)
  int g = b * CH + c;
  float bcc = bc[c];
  #pragma unroll
  for (int r = 0; r < KSEL; ++r) dout[(size_t)r * (NB * CH) + g] = bcc;
}

// ---------------- v[b][e] += sum_{c in chunk} p[b][c] * Wc[c][e] ----------------
__global__ __launch_bounds__(256) void colmm_kernel(const float* __restrict__ S,
                                                    const float* __restrict__ M,
                                                    float* __restrict__ O) {
  __shared__ float Sl[128][32];
  int t = threadIdx.x;
  int e0 = (blockIdx.x & 3) * 256, c0 = (blockIdx.x >> 2) * 128;
  for (int i = t; i < 4096; i += 256) {
    int c = i >> 5, b = i & 31;
    Sl[c][b] = S[b * CH + c0 + c];
  }
  __syncthreads();
  int e = e0 + t;
  float acc[32];
  #pragma unroll
  for (int b = 0; b < 32; ++b) acc[b] = 0.f;
  for (int c = 0; c < 128; ++c) {
    float wv = M[(size_t)(c0 + c) * CH + e];
    #pragma unroll
    for (int b = 0; b < 32; ++b) acc[b] += Sl[c][b] * wv;
  }
  #pragma unroll
  for (int b = 0; b < 32; ++b) atomicAdd(&O[b * CH + e], acc[b]);
}

// ---------------- logits s[b][l] = x[b][l][:] . v[b][:] ----------------
__global__ __launch_bounds__(256) void logits_kernel(const float* __restrict__ x,
                                                     const float* __restrict__ v,
                                                     float* __restrict__ s) {
  __shared__ float4 vl[256];
  int b = blockIdx.y, chunk = blockIdx.x, t = threadIdx.x;
  vl[t] = ((const float4*)(v + b * CH))[t];
  __syncthreads();
  int wv = t >> 6, lane = t & 63;
  for (int it = 0; it < 8; ++it) {
    int l = chunk * 32 + it * 4 + wv;
    const float4* xr = (const float4*)(x + ((size_t)b * L_SEQ + l) * CH);
    float acc = 0.f;
    #pragma unroll
    for (int rep = 0; rep < 4; ++rep) {
      float4 a = xr[rep * 64 + lane];
      float4 c = vl[rep * 64 + lane];
      acc += a.x * c.x + a.y * c.y + a.z * c.z + a.w * c.w;
    }
    #pragma unroll
    for (int off = 32; off; off >>= 1) acc += __shfl_xor(acc, off);
    if (lane == 0) s[b * L_SEQ + l] = acc;
  }
}

// ---------------- top-20 (desc, ties -> lower index), register-resident ------------
__global__ __launch_bounds__(256) void topk_kernel(const float* __restrict__ s,
                                                   int* __restrict__ idx_out) {
  int b = blockIdx.x, t = threadIdx.x;
  int lane = t & 63, w = t >> 6;
  __shared__ float lv[4];
  __shared__ int   li[4];
  float v[8];
  #pragma unroll
  for (int j = 0; j < 8; ++j) v[j] = s[b * L_SEQ + j * 256 + t];
  for (int k = 0; k < KSEL; ++k) {
    float bv = -INFINITY; int bi = 1 << 30;
    #pragma unroll
    for (int j = 0; j < 8; ++j) {
      int gi = j * 256 + t;
      if (v[j] > bv || (v[j] == bv && gi < bi)) { bv = v[j]; bi = gi; }
    }
    #pragma unroll
    for (int off = 32; off; off >>= 1) {
      float ov = __shfl_xor(bv, off); int oi = __shfl_xor(bi, off);
      if (ov > bv || (ov == bv && oi < bi)) { bv = ov; bi = oi; }
    }
    if (lane == 0) { lv[w] = bv; li[w] = bi; }
    __syncthreads();
    float fv = lv[0]; int fi = li[0];
    #pragma unroll
    for (int w2 = 1; w2 < 4; ++w2) {
      float ov = lv[w2]; int oi = li[w2];
      if (ov > fv || (ov == fv && oi < fi)) { fv = ov; fi = oi; }
    }
    if (t == 0) idx_out[b * KSEL + k] = fi;
    if ((fi & 255) == t) v[fi >> 8] = -INFINITY;
    __syncthreads();
  }
}

extern "C" void kernel_launch(void* const* d_in, const int* in_sizes, int n_in,
                              void* d_out, int out_size, void* d_ws, size_t ws_size,
                              hipStream_t stream) {
  const float* x   = (const float*)d_in[0];
  const float* W   = (const float*)d_in[1];
  const float* b   = (const float*)d_in[2];
  const float* W1  = (const float*)d_in[3];
  const float* b1  = (const float*)d_in[4];
  const float* Wm  = (const float*)d_in[5];
  const float* bm  = (const float*)d_in[6];
  const float* Wa  = (const float*)d_in[7];
  const float* ba  = (const float*)d_in[8];
  const float* g1w = (const float*)d_in[9];
  const float* g1b = (const float*)d_in[10];
  const float* g2w = (const float*)d_in[11];
  const float* g2b = (const float*)d_in[12];

  float* wsf = (float*)d_ws;
  float*    xsum = wsf + WS_XSUM;
  unsigned* ymax = (unsigned*)(wsf + WS_YMAX);
  float*    m1   = wsf + WS_M1;
  float*    amax = wsf + WS_AMAX;
  float*    t1   = wsf + WS_T1;
  float*    t2   = wsf + WS_T2;
  float*    p    = wsf + WS_P;
  float*    vvec = wsf + WS_V;
  float*    sbuf = wsf + WS_S;
  int*      tidx = (int*)(wsf + WS_TOPK);
  float*    bcv  = wsf + WS_BC;
  float*    Wc   = wsf + WS_WC;
  uint4*    wpak = (uint4*)(wsf + WS_WPAK);
  uint4*    wtpak = (uint4*)(wsf + WS_WTPAK);   // later reused as packed Wc

  // fused prologue: packw + zero(xsum/ymax/v), packwt + zero(Wc), bc
  prep_kernel<<<dim3(32, 20), 256, 0, stream>>>(W, W1, b, b1, wpak, wtpak, wsf, bcv);
  // mean standalone (must not co-reside with the MFMA gemm -> L2 pollution)
  mean_kernel<<<dim3(32, 32), 256, 0, stream>>>(x, xsum);
  // fused: big gemm+colmax || wc_gemm
  fused3_kernel<<<2176, 256, 0, stream>>>(x, wpak, ymax, W1, wtpak, Wc);
  // fused: repack Wc || poolmix
  mid_kernel<<<384, 256, 0, stream>>>(Wc, wtpak, xsum, ymax, W, b, m1, amax);

  lin2_kernel<<<256, 256, 0, stream>>>(m1, amax, Wm, bm, Wa, ba, t1, t2);
  gnp_kernel<<<32, 1024, 0, stream>>>(t1, t2, g1w, g1b, g2w, g2b, p, bcv, (float*)d_out);
  colmm_kernel<<<32, 256, 0, stream>>>(p, Wc, vvec);              // v = Wc^T p
  logits_kernel<<<dim3(64, 32), 256, 0, stream>>>(x, vvec, sbuf);
  topk_kernel<<<32, 256, 0, stream>>>(sbuf, tidx);
  out_gemm<<<dim3(20, 8), 256, 0, stream>>>(x, tidx, wtpak, (float*)d_out);  // K-split x8, atomic
}

// Round 5
// 886.261 us; speedup vs baseline: 1.1344x; 1.1344x over previous
//
#include <hip/hip_runtime.h>

#define L_SEQ 2048
#define CH    1024
#define NB    32
#define KSEL  20

typedef short v8s  __attribute__((ext_vector_type(8)));
typedef float v16f __attribute__((ext_vector_type(16)));

// ---------------- workspace layout (float offsets) ----------------
#define WS_XSUM   0          // [32*1024] f32   column sums of x
#define WS_YMAX   32768      // [32*1024] u32   encoded col-max of y
#define WS_M1     65536      // [32*1024] f32   mean-pool @ W^T + b
#define WS_AMAX   98304      // [32*1024] f32   decoded max-pool + b
#define WS_T1     131072     // [32*1024] f32
#define WS_T2     163840     // [32*1024] f32
#define WS_P      196608     // [32*1024] f32   gn1(t1)+gn2(t2)
#define WS_V      294912     // [32*1024] f32   v = Wc^T p
#define WS_S      327680     // [32*2048] f32   logit sums
#define WS_TOPK   393216     // [640] int
#define WS_BC     394240     // [1024] f32      bc = W1 b + b1
#define WS_WC     395264     // [1024*1024] f32 Wc = W1 W (row-major [d][c])
#define WS_WPAK   1443840    // 4 MB: packed W  (frag-major split-bf16)
#define WS_WTPAK  2492416    // 4 MB: packed W^T; REUSED later for packed Wc

// ---------------- fp32 -> (hi,lo) bf16 split, 8 elems -> two uint4 ----------------
__device__ __forceinline__ void split8(float4 qa, float4 qb, uint4& hi, uint4& lo) {
  float f[8] = {qa.x, qa.y, qa.z, qa.w, qb.x, qb.y, qb.z, qb.w};
  unsigned h[8], l[8];
  #pragma unroll
  for (int e = 0; e < 8; ++e) {
    unsigned u  = __float_as_uint(f[e]);
    unsigned hu = u & 0xFFFF0000u;                 // truncated hi bf16
    float lf    = f[e] - __uint_as_float(hu);      // residual
    h[e] = u >> 16;
    l[e] = __float_as_uint(lf) >> 16;              // truncated lo bf16
  }
  hi.x = h[0] | (h[1] << 16); hi.y = h[2] | (h[3] << 16);
  hi.z = h[4] | (h[5] << 16); hi.w = h[6] | (h[7] << 16);
  lo.x = l[0] | (l[1] << 16); lo.y = l[2] | (l[3] << 16);
  lo.z = l[4] | (l[5] << 16); lo.w = l[6] | (l[7] << 16);
}

// ---------------- pack body: row-major M -> frag-major split-bf16 ----------------
// chunk (Rw, kt) = 1024 uint4; slot = ((r>>5)*2 + (p>>1))*128 + (p&1)*32 + (r&31)
__device__ __forceinline__ void pack_row_body(const float* __restrict__ W,
                                              uint4* __restrict__ wp,
                                              int Rw, int kt, int t) {
  const float* wb = W + (size_t)Rw * 128 * CH;
  uint4* out = wp + ((size_t)Rw * 32 + kt) * 1024;
  #pragma unroll
  for (int pass = 0; pass < 2; ++pass) {
    int idx = pass * 256 + t;
    int r = idx >> 2, p = idx & 3;
    const float* ap = wb + (size_t)r * CH + kt * 32 + p * 8;
    float4 f0 = *(const float4*)ap;
    float4 f1 = *(const float4*)(ap + 4);
    uint4 hi, lo;
    split8(f0, f1, hi, lo);
    int slot = ((r >> 5) * 2 + (p >> 1)) * 128 + (p & 1) * 32 + (r & 31);
    out[slot] = hi;
    out[slot + 64] = lo;
  }
}

// ---------------- pack body: W^T (LDS transpose) -> frag-major split-bf16 --------
__device__ __forceinline__ void pack_tr_body(const float* __restrict__ W,
                                             uint4* __restrict__ wtp,
                                             int cc, int kt, int t,
                                             float (*__restrict__ Wl)[129]) {
  #pragma unroll
  for (int it = 0; it < 16; ++it) {
    int idx = it * 256 + t;
    int el = idx >> 7, cl = idx & 127;
    Wl[el][cl] = W[(size_t)(kt * 32 + el) * CH + cc * 128 + cl];
  }
  __syncthreads();
  uint4* out = wtp + ((size_t)cc * 32 + kt) * 1024;
  #pragma unroll
  for (int pass = 0; pass < 2; ++pass) {
    int sid = pass * 256 + t;
    int r = sid >> 2, p = sid & 3;
    float f[8];
    #pragma unroll
    for (int q = 0; q < 8; ++q) f[q] = Wl[p * 8 + q][r];
    float4 f0 = {f[0], f[1], f[2], f[3]}, f1 = {f[4], f[5], f[6], f[7]};
    uint4 hi, lo;
    split8(f0, f1, hi, lo);
    int slot = ((r >> 5) * 2 + (p >> 1)) * 128 + (p & 1) * 32 + (r & 31);
    out[slot] = hi;
    out[slot + 64] = lo;
  }
}

// ---------------- fused prologue: pack W, pack W^T, bc = W1 b + b1, zero-inits ----
// grid (32, 20): y 0..7 packw + zero xsum/ymax/v; y 8..15 packwt + zero Wc;
//                y 16..19 bc. No intra-kernel consumers of the zeroed buffers.
__global__ __launch_bounds__(256) void prep_kernel(const float* __restrict__ W,
                                                   const float* __restrict__ W1,
                                                   const float* __restrict__ b,
                                                   const float* __restrict__ b1,
                                                   uint4* __restrict__ wp,
                                                   uint4* __restrict__ wtp,
                                                   float* __restrict__ wsf,
                                                   float* __restrict__ bc) {
  __shared__ float Wl[32][129];
  int t = threadIdx.x, x = blockIdx.x, y = blockIdx.y;
  if (y < 8) {
    int flat = (y * 32 + x) * 256 + t;          // [0, 65536): xsum + ymax
    wsf[WS_XSUM + flat] = 0.f;
    if (flat < 32768) wsf[WS_V + flat] = 0.f;
    pack_row_body(W, wp, y, x, t);
  } else if (y < 16) {
    int tid = ((y - 8) * 32 + x) * 256 + t;     // [0, 65536): zero Wc (1M floats)
    float4* wc4 = (float4*)(wsf + WS_WC);
    #pragma unroll
    for (int r = 0; r < 4; ++r) wc4[(size_t)tid * 4 + r] = float4{0.f, 0.f, 0.f, 0.f};
    pack_tr_body(W, wtp, y - 8, x, t, Wl);
  } else {
    int bk = (y - 16) * 32 + x;                 // [0, 128)
    int d = bk * 8 + (t >> 5);
    int lane = t & 31;
    const float4* wr = (const float4*)(W1 + (size_t)d * CH);
    const float4* br = (const float4*)b;
    float acc = 0.f;
    #pragma unroll
    for (int c = lane; c < 256; c += 32) {
      float4 a = wr[c], m = br[c];
      acc += a.x * m.x + a.y * m.y + a.z * m.z + a.w * m.w;
    }
    #pragma unroll
    for (int off = 16; off; off >>= 1) acc += __shfl_xor(acc, off);
    if (lane == 0) bc[d] = acc + b1[d];
  }
}

// ---------------- shared GEMM K-loop core ----------------
// Block 128m x 256n, 4 waves, wave w = wn: tile 128m x 64n (i:4 m-tiles, j:2 n-tiles).
// A: f32 -> split -> LDS dbuf (conflict-free). B: packed frag direct from global (L2).
// NOTE: the split+store of kt+1 is at END of kt (after s1), NOT mid-kt. Round-4
// postmortem: mid-kt placement consumed A ~300cy after issue vs ~900cy HBM latency
// -> exposed vmcnt stall every kt (MfmaUtil 57->40). End-of-kt gives ~1 full kt of
// cover and is the round-1-proven placement.
template<bool FOURTH, int NKT>
__device__ __forceinline__ void gemm_core(const float* __restrict__ arow,
                                          const uint4* __restrict__ wbB,
                                          const int cgbase,
                                          uint4 (*__restrict__ smA)[1024],
                                          const int w, const int lane,
                                          v16f acc[4][2]) {
  {  // stage kt=0 into buf 0
    float4 p0 = *(const float4*)(arow);
    float4 p1 = *(const float4*)(arow + 4);
    float4 p2 = *(const float4*)(arow + 16);
    float4 p3 = *(const float4*)(arow + 20);
    uint4 hi, lo;
    split8(p0, p1, hi, lo);
    smA[0][(w * 2 + 0) * 128 + lane] = hi;
    smA[0][(w * 2 + 0) * 128 + 64 + lane] = lo;
    split8(p2, p3, hi, lo);
    smA[0][(w * 2 + 1) * 128 + lane] = hi;
    smA[0][(w * 2 + 1) * 128 + 64 + lane] = lo;
  }
  v8s bc[4], bn[4];
  #pragma unroll
  for (int j = 0; j < 2; ++j) {
    bc[j * 2]     = *(const v8s*)&wbB[((cgbase + j) * 2 + 0) * 128];
    bc[j * 2 + 1] = *(const v8s*)&wbB[((cgbase + j) * 2 + 0) * 128 + 64];
  }
  __syncthreads();

  for (int kt = 0; kt < NKT; ++kt) {
    const int cur = kt & 1;
    float4 q0, q1, q2, q3;
    if (kt < NKT - 1) {                 // issue next A-slice loads early
      const float* an = arow + (kt + 1) * 32;
      q0 = *(const float4*)(an);
      q1 = *(const float4*)(an + 4);
      q2 = *(const float4*)(an + 16);
      q3 = *(const float4*)(an + 20);
    }
    #pragma unroll
    for (int s = 0; s < 2; ++s) {
      const int nkt = s ? kt + 1 : kt, ns = s ^ 1;
      if (nkt < NKT) {                  // prefetch next B half-slice (4 loads)
        #pragma unroll
        for (int j = 0; j < 2; ++j) {
          bn[j * 2]     = *(const v8s*)&wbB[(size_t)nkt * 1024 + ((cgbase + j) * 2 + ns) * 128];
          bn[j * 2 + 1] = *(const v8s*)&wbB[(size_t)nkt * 1024 + ((cgbase + j) * 2 + ns) * 128 + 64];
        }
      }
      v8s ah[4], al[4];
      #pragma unroll
      for (int i = 0; i < 4; ++i) {
        int base = (i * 2 + s) * 128 + lane;
        ah[i] = *(const v8s*)&smA[cur][base];
        al[i] = *(const v8s*)&smA[cur][base + 64];
      }
      #pragma unroll
      for (int j = 0; j < 2; ++j) {
        v8s bh = bc[j * 2], bl = bc[j * 2 + 1];
        #pragma unroll
        for (int i = 0; i < 4; ++i) {
          acc[i][j] = __builtin_amdgcn_mfma_f32_32x32x16_bf16(ah[i], bh, acc[i][j], 0, 0, 0);
          acc[i][j] = __builtin_amdgcn_mfma_f32_32x32x16_bf16(ah[i], bl, acc[i][j], 0, 0, 0);
          acc[i][j] = __builtin_amdgcn_mfma_f32_32x32x16_bf16(al[i], bh, acc[i][j], 0, 0, 0);
          if (FOURTH)
            acc[i][j] = __builtin_amdgcn_mfma_f32_32x32x16_bf16(al[i], bl, acc[i][j], 0, 0, 0);
        }
      }
      #pragma unroll
      for (int e = 0; e < 4; ++e) bc[e] = bn[e];
    }
    if (kt < NKT - 1) {                 // end-of-kt: split + store kt+1 into other buf
      uint4 hi, lo;
      split8(q0, q1, hi, lo);
      smA[cur ^ 1][(w * 2 + 0) * 128 + lane] = hi;
      smA[cur ^ 1][(w * 2 + 0) * 128 + 64 + lane] = lo;
      split8(q2, q3, hi, lo);
      smA[cur ^ 1][(w * 2 + 1) * 128 + lane] = hi;
      smA[cur ^ 1][(w * 2 + 1) * 128 + 64 + lane] = lo;
    }
    __syncthreads();
  }
}

// ---------------- fused: big GEMM+colmax  ||  mean(x)  ||  Wc = W1@W ----------------
// grid = 3200 = 128 groups of 25: r<16 -> gemm block (2048), r<24 -> mean (1024),
// r==24 -> wc (128). All three depend only on prep. Round-4 showed serial mean
// costs ~45us vs ~12us of in-fusion pollution -> fusion is net-positive.
__global__ __launch_bounds__(256, 2) void fused3_kernel(const float* __restrict__ X,
                                                        const uint4* __restrict__ wp,
                                                        unsigned* __restrict__ ymax,
                                                        float* __restrict__ xsum,
                                                        const float* __restrict__ W1,
                                                        const uint4* __restrict__ wtp,
                                                        float* __restrict__ Wc) {
  __shared__ uint4 smA[2][1024];        // 32 KB dbuf -> 2 blocks/CU
  const int id = blockIdx.x;
  const int g = id / 25, r = id % 25;
  const int t = threadIdx.x, lane = t & 63, w = t >> 6;

  if (r < 16) {
    // ---------- big GEMM + column max (3-term split-bf16) ----------
    const int k = g * 16 + r;
    const int strip = k & 3, mt = k >> 2;
    const int batch = mt >> 4;
    const float* arow = X + (size_t)(mt * 128 + w * 32 + (lane & 31)) * CH + (lane >> 5) * 8;
    v16f acc[4][2];
    #pragma unroll
    for (int i = 0; i < 4; ++i)
      #pragma unroll
      for (int j = 0; j < 2; ++j)
        #pragma unroll
        for (int e = 0; e < 16; ++e) acc[i][j][e] = 0.f;
    const uint4* wbB = wp + (size_t)(strip * 2 + (w >> 1)) * 32768 + lane;
    gemm_core<false, 32>(arow, wbB, (w & 1) * 2, smA, w, lane, acc);

    // column-max epilogue: 32x32 C/D layout, col = lane&31
    #pragma unroll
    for (int j = 0; j < 2; ++j) {
      float m = -INFINITY;
      #pragma unroll
      for (int i = 0; i < 4; ++i)
        #pragma unroll
        for (int e = 0; e < 16; ++e) m = fmaxf(m, acc[i][j][e]);
      m = fmaxf(m, __shfl_xor(m, 32));
      if (lane < 32) {
        int col = strip * 256 + w * 64 + j * 32 + lane;
        unsigned u = __float_as_uint(m);
        unsigned enc = (m >= 0.f) ? (u | 0x80000000u) : ~u;  // order-preserving encode
        atomicMax(&ymax[batch * CH + col], enc);
      }
    }
  } else if (r < 24) {
    // ---------- column sums of x (atomic partial sums) ----------
    const int m = g * 8 + (r - 16);
    const int b = m >> 5, chunk = m & 31;
    const float4* bp = (const float4*)(X + ((size_t)b * L_SEQ + (size_t)chunk * 64) * CH);
    float sx = 0.f, sy = 0.f, sz = 0.f, sw = 0.f;
    #pragma unroll 4
    for (int l = 0; l < 64; ++l) {
      float4 a = bp[l * 256 + t];
      sx += a.x; sy += a.y; sz += a.z; sw += a.w;
    }
    float* dst = xsum + b * CH + t * 4;
    atomicAdd(dst + 0, sx); atomicAdd(dst + 1, sy);
    atomicAdd(dst + 2, sz); atomicAdd(dst + 3, sw);
  } else {
    // ---------- Wc = W1 @ W (4-term, K-split x4, atomic reduction) ----------
    const int c = g;                    // 0..127
    const int blk = c >> 2, chunk = c & 3;
    const int strip = blk & 3, mt = blk >> 2;     // mt 0..7
    const float* arow = W1 + (size_t)(mt * 128 + w * 32 + (lane & 31)) * CH
                           + (lane >> 5) * 8 + chunk * 256;
    v16f acc[4][2];
    #pragma unroll
    for (int i = 0; i < 4; ++i)
      #pragma unroll
      for (int j = 0; j < 2; ++j)
        #pragma unroll
        for (int e = 0; e < 16; ++e) acc[i][j][e] = 0.f;
    const uint4* wbB = wtp + (size_t)(strip * 2 + (w >> 1)) * 32768
                           + (size_t)chunk * (8 * 1024) + lane;
    gemm_core<true, 8>(arow, wbB, (w & 1) * 2, smA, w, lane, acc);

    #pragma unroll
    for (int i = 0; i < 4; ++i)
      #pragma unroll
      for (int j = 0; j < 2; ++j)
        #pragma unroll
        for (int rr = 0; rr < 16; ++rr) {
          int row = (rr & 3) + 8 * (rr >> 2) + 4 * (lane >> 5);
          int grow = mt * 128 + i * 32 + row;
          int gcol = strip * 256 + w * 64 + j * 32 + (lane & 31);
          atomicAdd(&Wc[(size_t)grow * CH + gcol], acc[i][j][rr]);
        }
  }
}

// ---------------- out += x[sel] @ Wc^T (4-term; bias pre-broadcast by gnp) -------
// K-split x8 (blockIdx.y = chunk, 4 kt each); fp32 atomic reduction into d_out.
__global__ __launch_bounds__(256, 2) void out_gemm(const float* __restrict__ X,
                                                   const int* __restrict__ idx,
                                                   const uint4* __restrict__ wcp,
                                                   float* __restrict__ C) {
  __shared__ uint4 smA[2][1024];
  const int t = threadIdx.x, lane = t & 63, w = t >> 6;
  const int blk = blockIdx.x, chunk = blockIdx.y;   // blk 0..19, chunk 0..7
  const int strip = blk & 3, mt = blk >> 2;         // mt 0..4 (640 rows exactly)
  const int rr = mt * 128 + w * 32 + (lane & 31);
  const int grow_a = (rr / KSEL) * L_SEQ + idx[rr];
  const float* arow = X + (size_t)grow_a * CH + (lane >> 5) * 8 + chunk * 128;
  v16f acc[4][2];
  #pragma unroll
  for (int i = 0; i < 4; ++i)
    #pragma unroll
    for (int j = 0; j < 2; ++j)
      #pragma unroll
      for (int e = 0; e < 16; ++e) acc[i][j][e] = 0.f;
  const uint4* wbB = wcp + (size_t)(strip * 2 + (w >> 1)) * 32768
                         + (size_t)chunk * (4 * 1024) + lane;
  gemm_core<true, 4>(arow, wbB, (w & 1) * 2, smA, w, lane, acc);

  #pragma unroll
  for (int i = 0; i < 4; ++i)
    #pragma unroll
    for (int j = 0; j < 2; ++j)
      #pragma unroll
      for (int r = 0; r < 16; ++r) {
        int row = (r & 3) + 8 * (r >> 2) + 4 * (lane >> 5);
        int grow = mt * 128 + i * 32 + row;
        int gcol = strip * 256 + w * 64 + j * 32 + (lane & 31);
        atomicAdd(&C[(size_t)grow * CH + gcol], acc[i][j][r]);
      }
}

// ---------------- fused: repack Wc  ||  poolmix ----------------
// id<256: wtpak := packed Wc; id>=256: m1 = xsum@W^T/2048 + b, amax = decode + b.
__global__ __launch_bounds__(256) void mid_kernel(const float* __restrict__ Wc,
                                                  uint4* __restrict__ wtp,
                                                  const float* __restrict__ xsum,
                                                  const unsigned* __restrict__ ymax,
                                                  const float* __restrict__ W,
                                                  const float* __restrict__ bias,
                                                  float* __restrict__ m1,
                                                  float* __restrict__ amax) {
  int id = blockIdx.x, t = threadIdx.x;
  if (id < 256) {
    pack_row_body(Wc, wtp, id >> 5, id & 31, t);
  } else {
    int bk = id - 256;                  // 0..127
    int iid = bk * 256 + t;
    unsigned u = ymax[iid];
    float f = (u & 0x80000000u) ? __uint_as_float(u & 0x7FFFFFFFu) : __uint_as_float(~u);
    amax[iid] = f + bias[iid & (CH - 1)];

    int d = bk * 8 + (t >> 5);
    int b = t & 31;
    const float4* Ir = (const float4*)(xsum + b * CH);
    const float4* Mr = (const float4*)(W + (size_t)d * CH);
    float acc = 0.f;
    #pragma unroll 4
    for (int c = 0; c < CH / 4; ++c) {
      float4 a = Ir[c], m = Mr[c];
      acc += a.x * m.x + a.y * m.y + a.z * m.z + a.w * m.w;
    }
    m1[b * CH + d] = acc * (1.f / 2048.f) + bias[d];
  }
}

// ---------------- t1 = m1@Wm^T + bm ; t2 = amax@Wa^T + ba ----------------
__global__ __launch_bounds__(256) void lin2_kernel(const float* __restrict__ m1,
                                                   const float* __restrict__ amax,
                                                   const float* __restrict__ Wm,
                                                   const float* __restrict__ bm,
                                                   const float* __restrict__ Wa,
                                                   const float* __restrict__ ba,
                                                   float* __restrict__ t1,
                                                   float* __restrict__ t2) {
  int t = threadIdx.x;
  int which = blockIdx.x >> 7, bk = blockIdx.x & 127;
  const float* I = which ? amax : m1;
  const float* M = which ? Wa : Wm;
  const float* bb = which ? ba : bm;
  float* O = which ? t2 : t1;
  int d = bk * 8 + (t >> 5);
  int b = t & 31;
  const float4* Ir = (const float4*)(I + b * CH);
  const float4* Mr = (const float4*)(M + (size_t)d * CH);
  float acc = 0.f;
  #pragma unroll 4
  for (int c = 0; c < CH / 4; ++c) {
    float4 a = Ir[c], m = Mr[c];
    acc += a.x * m.x + a.y * m.y + a.z * m.z + a.w * m.w;
  }
  O[b * CH + d] = acc + bb[d];
}

// ---------------- GroupNorm both branches, emit p = gn1(t1)+gn2(t2) ----------------
// Also pre-broadcasts bc into d_out so K-split out_gemm can atomicAdd.
__global__ __launch_bounds__(1024) void gnp_kernel(const float* __restrict__ t1,
                                                   const float* __restrict__ t2,
                                                   const float* __restrict__ g1w, const float* __restrict__ g1b,
                                                   const float* __restrict__ g2w, const float* __restrict__ g2b,
                                                   float* __restrict__ p,
                                                   const float* __restrict__ bc,
                                                   float* __restrict__ dout) {
  int b = blockIdx.x, c = threadIdx.x;
  float v1 = t1[b * CH + c], v2 = t2[b * CH + c];
  float s1 = v1, s2 = v2;
  #pragma unroll
  for (int off = 16; off; off >>= 1) { s1 += __shfl_xor(s1, off); s2 += __shfl_xor(s2, off); }
  float d1 = v1 - s1 * (1.f / 32.f), d2 = v2 - s2 * (1.f / 32.f);
  float q1 = d1 * d1, q2 = d2 * d2;
  #pragma unroll
  for (int off = 16; off; off >>= 1) { q1 += __shfl_xor(q1, off); q2 += __shfl_xor(q2, off); }
  float o1 = d1 * rsqrtf(q1 * (1.f / 32.f) + 1e-5f) * g1w[c] + g1b[c];
  float o2 = d2 * rsqrtf(q2 * (1.f / 32.f) + 1e-5f) * g2w[c] + g2b[c];
  p[b * CH + c] = o1 + o2;

  // d_out[r*32 + b][c] = bc[c] for r = 0..19  (flat = r*32768 + b*1024 + c)
  int g = b * CH + c;
  float bcc = bc[c];
  #pragma unroll
  for (int r = 0; r < KSEL; ++r) dout[(size_t)r * (NB * CH) + g] = bcc;
}

// ---------------- v[b][e] += sum_{c in chunk} p[b][c] * Wc[c][e] ----------------
__global__ __launch_bounds__(256) void colmm_kernel(const float* __restrict__ S,
                                                    const float* __restrict__ M,
                                                    float* __restrict__ O) {
  __shared__ float Sl[128][32];
  int t = threadIdx.x;
  int e0 = (blockIdx.x & 3) * 256, c0 = (blockIdx.x >> 2) * 128;
  for (int i = t; i < 4096; i += 256) {
    int c = i >> 5, b = i & 31;
    Sl[c][b] = S[b * CH + c0 + c];
  }
  __syncthreads();
  int e = e0 + t;
  float acc[32];
  #pragma unroll
  for (int b = 0; b < 32; ++b) acc[b] = 0.f;
  for (int c = 0; c < 128; ++c) {
    float wv = M[(size_t)(c0 + c) * CH + e];
    #pragma unroll
    for (int b = 0; b < 32; ++b) acc[b] += Sl[c][b] * wv;
  }
  #pragma unroll
  for (int b = 0; b < 32; ++b) atomicAdd(&O[b * CH + e], acc[b]);
}

// ---------------- logits s[b][l] = x[b][l][:] . v[b][:] ----------------
__global__ __launch_bounds__(256) void logits_kernel(const float* __restrict__ x,
                                                     const float* __restrict__ v,
                                                     float* __restrict__ s) {
  __shared__ float4 vl[256];
  int b = blockIdx.y, chunk = blockIdx.x, t = threadIdx.x;
  vl[t] = ((const float4*)(v + b * CH))[t];
  __syncthreads();
  int wv = t >> 6, lane = t & 63;
  for (int it = 0; it < 8; ++it) {
    int l = chunk * 32 + it * 4 + wv;
    const float4* xr = (const float4*)(x + ((size_t)b * L_SEQ + l) * CH);
    float acc = 0.f;
    #pragma unroll
    for (int rep = 0; rep < 4; ++rep) {
      float4 a = xr[rep * 64 + lane];
      float4 c = vl[rep * 64 + lane];
      acc += a.x * c.x + a.y * c.y + a.z * c.z + a.w * c.w;
    }
    #pragma unroll
    for (int off = 32; off; off >>= 1) acc += __shfl_xor(acc, off);
    if (lane == 0) s[b * L_SEQ + l] = acc;
  }
}

// ---------------- top-20 (desc, ties -> lower index), register-resident ------------
__global__ __launch_bounds__(256) void topk_kernel(const float* __restrict__ s,
                                                   int* __restrict__ idx_out) {
  int b = blockIdx.x, t = threadIdx.x;
  int lane = t & 63, w = t >> 6;
  __shared__ float lv[4];
  __shared__ int   li[4];
  float v[8];
  #pragma unroll
  for (int j = 0; j < 8; ++j) v[j] = s[b * L_SEQ + j * 256 + t];
  for (int k = 0; k < KSEL; ++k) {
    float bv = -INFINITY; int bi = 1 << 30;
    #pragma unroll
    for (int j = 0; j < 8; ++j) {
      int gi = j * 256 + t;
      if (v[j] > bv || (v[j] == bv && gi < bi)) { bv = v[j]; bi = gi; }
    }
    #pragma unroll
    for (int off = 32; off; off >>= 1) {
      float ov = __shfl_xor(bv, off); int oi = __shfl_xor(bi, off);
      if (ov > bv || (ov == bv && oi < bi)) { bv = ov; bi = oi; }
    }
    if (lane == 0) { lv[w] = bv; li[w] = bi; }
    __syncthreads();
    float fv = lv[0]; int fi = li[0];
    #pragma unroll
    for (int w2 = 1; w2 < 4; ++w2) {
      float ov = lv[w2]; int oi = li[w2];
      if (ov > fv || (ov == fv && oi < fi)) { fv = ov; fi = oi; }
    }
    if (t == 0) idx_out[b * KSEL + k] = fi;
    if ((fi & 255) == t) v[fi >> 8] = -INFINITY;
    __syncthreads();
  }
}

extern "C" void kernel_launch(void* const* d_in, const int* in_sizes, int n_in,
                              void* d_out, int out_size, void* d_ws, size_t ws_size,
                              hipStream_t stream) {
  const float* x   = (const float*)d_in[0];
  const float* W   = (const float*)d_in[1];
  const float* b   = (const float*)d_in[2];
  const float* W1  = (const float*)d_in[3];
  const float* b1  = (const float*)d_in[4];
  const float* Wm  = (const float*)d_in[5];
  const float* bm  = (const float*)d_in[6];
  const float* Wa  = (const float*)d_in[7];
  const float* ba  = (const float*)d_in[8];
  const float* g1w = (const float*)d_in[9];
  const float* g1b = (const float*)d_in[10];
  const float* g2w = (const float*)d_in[11];
  const float* g2b = (const float*)d_in[12];

  float* wsf = (float*)d_ws;
  float*    xsum = wsf + WS_XSUM;
  unsigned* ymax = (unsigned*)(wsf + WS_YMAX);
  float*    m1   = wsf + WS_M1;
  float*    amax = wsf + WS_AMAX;
  float*    t1   = wsf + WS_T1;
  float*    t2   = wsf + WS_T2;
  float*    p    = wsf + WS_P;
  float*    vvec = wsf + WS_V;
  float*    sbuf = wsf + WS_S;
  int*      tidx = (int*)(wsf + WS_TOPK);
  float*    bcv  = wsf + WS_BC;
  float*    Wc   = wsf + WS_WC;
  uint4*    wpak = (uint4*)(wsf + WS_WPAK);
  uint4*    wtpak = (uint4*)(wsf + WS_WTPAK);   // later reused as packed Wc

  // fused prologue: packw + zero(xsum/ymax/v), packwt + zero(Wc), bc
  prep_kernel<<<dim3(32, 20), 256, 0, stream>>>(W, W1, b, b1, wpak, wtpak, wsf, bcv);
  // fused: big gemm+colmax || mean || wc_gemm  (all depend only on prep)
  fused3_kernel<<<3200, 256, 0, stream>>>(x, wpak, ymax, xsum, W1, wtpak, Wc);
  // fused: repack Wc || poolmix  (both depend only on fused3)
  mid_kernel<<<384, 256, 0, stream>>>(Wc, wtpak, xsum, ymax, W, b, m1, amax);

  lin2_kernel<<<256, 256, 0, stream>>>(m1, amax, Wm, bm, Wa, ba, t1, t2);
  gnp_kernel<<<32, 1024, 0, stream>>>(t1, t2, g1w, g1b, g2w, g2b, p, bcv, (float*)d_out);
  colmm_kernel<<<32, 256, 0, stream>>>(p, Wc, vvec);              // v = Wc^T p
  logits_kernel<<<dim3(64, 32), 256, 0, stream>>>(x, vvec, sbuf);
  topk_kernel<<<32, 256, 0, stream>>>(sbuf, tidx);
  out_gemm<<<dim3(20, 8), 256, 0, stream>>>(x, tidx, wtpak, (float*)d_out);  // K-split x8, atomic
}